// Round 6
// baseline (413.781 us; speedup 1.0000x reference)
//
#include <hip/hip_runtime.h>
#include <hip/hip_bf16.h>
#include <math.h>

// KAN layer, fused v2: per K-step (8 dims) each block featurizes its 128 rows
// (wave = dim -> params via scalar loads; f32x2 packed row-pair math) into a
// double-buffered padded LDS A-tile; B fragments stream L2->registers directly
// (no LDS for B). y = tanh(F @ W^T + silu-col + rs*x), F/W fp16, fp32 accum.

#define IN_DIM  512
#define OUT_DIM 512
#define FPI     12
#define KTOT    (IN_DIM * FPI)    // 6144
#define NBATCH  16384

#define PSTRIDE 64
#define WS_WH_OFF_F (PSTRIDE * IN_DIM)   // floats

#define BMF 128     // rows per block
#define BNF 256     // cols per block
#define LDA 104     // padded A stride (halfs): 52-dword rows -> conflict-free b128
#define NSTEPS 64   // 512 dims / 8 per step

typedef _Float16 half8 __attribute__((ext_vector_type(8)));
typedef _Float16 half4 __attribute__((ext_vector_type(4)));
typedef float f32x4 __attribute__((ext_vector_type(4)));
typedef float f32x2 __attribute__((ext_vector_type(2)));

// ---------------- kernel 1: per-dim knots + inverse denominators -----------
__global__ void kan_prep(const float* __restrict__ gsl, const float* __restrict__ gstart,
                         float* __restrict__ P) {
    int i = blockIdx.x * 256 + threadIdx.x;
    if (i >= IN_DIM) return;
    float t[15];
    float a = gstart[i];
    t[0] = a;
#pragma unroll
    for (int m = 0; m < 14; ++m) {
        float z = gsl[i * 14 + m];
        a += fmaxf(z, 0.f) + log1pf(__expf(-fabsf(z)));   // stable softplus
        t[m + 1] = a;
    }
    float* p = P + (size_t)i * PSTRIDE;
#pragma unroll
    for (int m = 0; m < 15; ++m) p[m] = t[m];
#pragma unroll
    for (int m = 0; m < 14; ++m) { float d = t[m+1] - t[m]; p[15+m] = 1.f / ((d == 0.f) ? 1.f : d); }
#pragma unroll
    for (int m = 0; m < 13; ++m) { float d = t[m+2] - t[m]; p[29+m] = 1.f / ((d == 0.f) ? 1.f : d); }
#pragma unroll
    for (int m = 0; m < 12; ++m) { float d = t[m+3] - t[m]; p[42+m] = 1.f / ((d == 0.f) ? 1.f : d); }
#pragma unroll
    for (int m = 54; m < 64; ++m) p[m] = 0.f;
}

// ---------------- kernel 2: pack [coeffs | base_weight] to fp16 ------------
__global__ void kan_packw(const float* __restrict__ coeffs, const float* __restrict__ bw,
                          _Float16* __restrict__ Wh) {
    int idx = blockIdx.x * 256 + threadIdx.x;   // idx = o*512 + i
    const float* src = coeffs + (size_t)idx * 11;
    union { _Float16 h[12]; float2 f2[3]; } u;
#pragma unroll
    for (int c = 0; c < 11; ++c) u.h[c] = (_Float16)src[c];
    u.h[11] = (_Float16)bw[idx];
    float2* dst = (float2*)(Wh + (size_t)idx * FPI);
    dst[0] = u.f2[0]; dst[1] = u.f2[1]; dst[2] = u.f2[2];
}

// ---------------- kernel 3: fused featurize + GEMM + epilogue --------------
__launch_bounds__(512, 2)
__global__ void kan_fused(const float* __restrict__ x, const float* __restrict__ P,
                          const _Float16* __restrict__ Wh, const float* __restrict__ rsp,
                          float* __restrict__ out) {
    __shared__ __align__(16) _Float16 A0[BMF][LDA];   // 26,624 B
    __shared__ __align__(16) _Float16 A1[BMF][LDA];   // 26,624 B

    const int tid = threadIdx.x;
    const int l = tid & 63;
    const int w = __builtin_amdgcn_readfirstlane(tid >> 6);  // wave 0..7
    // XCD swizzle (nwg=256): co-locate the two col-tiles of a row-block
    const int bid = blockIdx.x;
    const int wg = (bid & 7) * 32 + (bid >> 3);
    const int rt = wg >> 1, ct = wg & 1;
    const int b0 = rt * BMF, o0 = ct * BNF;

    // MFMA geometry: 8 waves = 2(row) x 4(col) tiles of 64x64
    const int wr = (w >> 2) * 64;
    const int wc = (w & 3) * 64;

    f32x4 acc[4][4];
    const f32x4 zz = {0.f, 0.f, 0.f, 0.f};
#pragma unroll
    for (int m = 0; m < 4; ++m)
#pragma unroll
        for (int n = 0; n < 4; ++n) acc[m][n] = zz;

    // per-lane bases
    const float* xp0 = x + (size_t)(b0 + l) * IN_DIM + w;          // row l,  dim s*8+w
    const float* xp1 = x + (size_t)(b0 + l + 64) * IN_DIM + w;     // row l+64
    const _Float16* gB = Wh + (size_t)(o0 + wc + (l & 15)) * KTOT + (l >> 4) * 8;
    const int ar = wr + (l & 15);
    const int ko = (l >> 4) * 8;

    // ---- featurize macro: dim = s*8 + w, rows (l, l+64), write to AB ----
#define FEATURIZE(s, AB)                                                        \
    {                                                                           \
        const float* ps = P + (size_t)((s) * 8 + w) * PSTRIDE;                  \
        f32x2 X = { xv.x, xv.y };                                               \
        f32x2 b[14];                                                            \
        _Pragma("unroll")                                                       \
        for (int m = 0; m < 14; ++m) {                                          \
            float tm = ps[m], tm1 = ps[m + 1];                                  \
            b[m].x = (X.x >= tm && X.x < tm1) ? 1.f : 0.f;                      \
            b[m].y = (X.y >= tm && X.y < tm1) ? 1.f : 0.f;                      \
        }                                                                       \
        _Pragma("unroll")                                                       \
        for (int m = 0; m < 13; ++m) {                                          \
            f32x2 dm = X - ps[m];                                               \
            f32x2 dp = X - ps[m + 2];                                           \
            b[m] = (dm * ps[15 + m]) * b[m] - (dp * ps[16 + m]) * b[m + 1];     \
        }                                                                       \
        _Pragma("unroll")                                                       \
        for (int m = 0; m < 12; ++m) {                                          \
            f32x2 dm = X - ps[m];                                               \
            f32x2 dp = X - ps[m + 3];                                           \
            b[m] = (dm * ps[29 + m]) * b[m] - (dp * ps[30 + m]) * b[m + 1];     \
        }                                                                       \
        _Pragma("unroll")                                                       \
        for (int m = 0; m < 11; ++m) {                                          \
            f32x2 dm = X - ps[m];                                               \
            f32x2 dp = X - ps[m + 4];                                           \
            b[m] = (dm * ps[42 + m]) * b[m] - (dp * ps[43 + m]) * b[m + 1];     \
        }                                                                       \
        f32x2 sil;                                                              \
        sil.x = X.x / (1.f + __expf(-X.x));                                     \
        sil.y = X.y / (1.f + __expf(-X.y));                                     \
        _Pragma("unroll")                                                       \
        for (int pt = 0; pt < 2; ++pt) {                                        \
            const int row = l + pt * 64;                                        \
            half4 h0 = { (_Float16)(pt ? b[0].y : b[0].x),                      \
                         (_Float16)(pt ? b[1].y : b[1].x),                      \
                         (_Float16)(pt ? b[2].y : b[2].x),                      \
                         (_Float16)(pt ? b[3].y : b[3].x) };                    \
            half4 h1 = { (_Float16)(pt ? b[4].y : b[4].x),                      \
                         (_Float16)(pt ? b[5].y : b[5].x),                      \
                         (_Float16)(pt ? b[6].y : b[6].x),                      \
                         (_Float16)(pt ? b[7].y : b[7].x) };                    \
            half4 h2 = { (_Float16)(pt ? b[8].y : b[8].x),                      \
                         (_Float16)(pt ? b[9].y : b[9].x),                      \
                         (_Float16)(pt ? b[10].y : b[10].x),                    \
                         (_Float16)(pt ? sil.y : sil.x) };                      \
            *(half4*)&AB[row][w * 12]     = h0;                                 \
            *(half4*)&AB[row][w * 12 + 4] = h1;                                 \
            *(half4*)&AB[row][w * 12 + 8] = h2;                                 \
        }                                                                       \
    }

    // ---- one pipeline step: MFMA(s) from Acur, featurize(s+1) -> Anxt ----
#define STEP(s, Acur, Anxt)                                                     \
    {                                                                           \
        half8 bf[4][3];                                                         \
        _Pragma("unroll")                                                       \
        for (int n = 0; n < 4; ++n)                                             \
            _Pragma("unroll")                                                   \
            for (int kk = 0; kk < 3; ++kk)                                      \
                bf[n][kk] = *(const half8*)&gB[(size_t)n * 16 * KTOT + (s) * 96 + kk * 32]; \
        if ((s) + 1 < NSTEPS) { FEATURIZE((s) + 1, Anxt); }                     \
        if ((s) + 2 < NSTEPS) {                                                 \
            xv2.x = xp0[((s) + 2) * 8]; xv2.y = xp1[((s) + 2) * 8];             \
        }                                                                       \
        _Pragma("unroll")                                                       \
        for (int kk = 0; kk < 3; ++kk) {                                        \
            half8 af[4];                                                        \
            _Pragma("unroll")                                                   \
            for (int m = 0; m < 4; ++m)                                         \
                af[m] = *(const half8*)&Acur[ar + m * 16][kk * 32 + ko];        \
            _Pragma("unroll")                                                   \
            for (int m = 0; m < 4; ++m)                                         \
                _Pragma("unroll")                                               \
                for (int n = 0; n < 4; ++n)                                     \
                    acc[m][n] = __builtin_amdgcn_mfma_f32_16x16x32_f16(af[m], bf[n][kk], acc[m][n], 0, 0, 0); \
        }                                                                       \
        __syncthreads();                                                        \
        xv = xv2;                                                               \
    }

    // prologue: featurize step 0 into A0, prefetch x for step 1
    f32x2 xv, xv2;
    xv.x = xp0[0]; xv.y = xp1[0];
    FEATURIZE(0, A0);
    xv.x = xp0[8]; xv.y = xp1[8];
    __syncthreads();

    for (int s = 0; s < NSTEPS; s += 2) {
        STEP(s,     A0, A1);
        STEP(s + 1, A1, A0);
    }

    // ---- epilogue: + rs*x, tanh, store ----
    const float rs = rsp[0];
    if (rs != 0.f) {
#pragma unroll
        for (int m = 0; m < 4; ++m)
#pragma unroll
            for (int n = 0; n < 4; ++n)
#pragma unroll
                for (int j = 0; j < 4; ++j) {
                    const int r = b0 + wr + m * 16 + (l >> 4) * 4 + j;
                    const int c = o0 + wc + n * 16 + (l & 15);
                    float v = acc[m][n][j] + rs * x[(size_t)r * IN_DIM + c];
                    float e = __expf(2.f * v);
                    out[(size_t)r * OUT_DIM + c] = 1.f - 2.f / (e + 1.f);
                }
    } else {
#pragma unroll
        for (int m = 0; m < 4; ++m)
#pragma unroll
            for (int n = 0; n < 4; ++n)
#pragma unroll
                for (int j = 0; j < 4; ++j) {
                    const int r = b0 + wr + m * 16 + (l >> 4) * 4 + j;
                    const int c = o0 + wc + n * 16 + (l & 15);
                    float v = acc[m][n][j];
                    float e = __expf(2.f * v);
                    out[(size_t)r * OUT_DIM + c] = 1.f - 2.f / (e + 1.f);
                }
    }
#undef STEP
#undef FEATURIZE
}

extern "C" void kernel_launch(void* const* d_in, const int* in_sizes, int n_in,
                              void* d_out, int out_size, void* d_ws, size_t ws_size,
                              hipStream_t stream) {
    const float* x      = (const float*)d_in[0];
    const float* coeffs = (const float*)d_in[1];
    const float* bw     = (const float*)d_in[2];
    const float* gsl    = (const float*)d_in[3];
    const float* gstart = (const float*)d_in[4];
    const float* rs     = (const float*)d_in[5];
    float* out = (float*)d_out;
    float* P   = (float*)d_ws;
    _Float16* Wh = (_Float16*)(P + WS_WH_OFF_F);

    kan_prep<<<2, 256, 0, stream>>>(gsl, gstart, P);
    kan_packw<<<1024, 256, 0, stream>>>(coeffs, bw, Wh);
    kan_fused<<<(NBATCH / BMF) * (OUT_DIM / BNF), 512, 0, stream>>>(x, P, Wh, rs, out);
}

// Round 7
// 303.944 us; speedup vs baseline: 1.3614x; 1.3614x over previous
//
#include <hip/hip_runtime.h>
#include <hip/hip_bf16.h>
#include <math.h>

// KAN layer, split v3:
//   (1) kan_prep:  grid knots + inverse denominators per input dim
//   (2) kan_packw: [coeffs | base_weight] -> fp16 W [512][6144]
//   (3) kan_feat:  wave=dim featurizer (params in SGPRs), F [16384][6144] fp16
//   (4) kan_gemm:  128x128 BK=64 MFMA GEMM, XOR-swizzled LDS (pre-swizzled
//                  global source + swizzled ds_read), fused tanh epilogue.

#define IN_DIM  512
#define OUT_DIM 512
#define FPI     12
#define KTOT    (IN_DIM * FPI)    // 6144
#define NBATCH  16384

#define PSTRIDE 64
#define WS_WH_OFF_F (PSTRIDE * IN_DIM)   // floats
#define WS_F_OFF_B  ((size_t)(PSTRIDE * IN_DIM * 4) + (size_t)OUT_DIM * KTOT * 2)

typedef _Float16 half8 __attribute__((ext_vector_type(8)));
typedef _Float16 half4 __attribute__((ext_vector_type(4)));
typedef float f32x4 __attribute__((ext_vector_type(4)));

__device__ __forceinline__ void gload16(const void* g, void* l) {
    __builtin_amdgcn_global_load_lds((const __attribute__((address_space(1))) void*)g,
                                     (__attribute__((address_space(3))) void*)l, 16, 0, 0);
}

// ---------------- kernel 1: per-dim knots + inverse denominators -----------
// P row (64 f32/dim): t[0..14]@0 | i1[0..13]@15 | i2[0..12]@29 | i3[0..11]@42
__global__ void kan_prep(const float* __restrict__ gsl, const float* __restrict__ gstart,
                         float* __restrict__ P) {
    int i = blockIdx.x * 256 + threadIdx.x;
    if (i >= IN_DIM) return;
    float t[15];
    float a = gstart[i];
    t[0] = a;
#pragma unroll
    for (int m = 0; m < 14; ++m) {
        float z = gsl[i * 14 + m];
        a += fmaxf(z, 0.f) + log1pf(__expf(-fabsf(z)));   // stable softplus
        t[m + 1] = a;
    }
    float* p = P + (size_t)i * PSTRIDE;
#pragma unroll
    for (int m = 0; m < 15; ++m) p[m] = t[m];
#pragma unroll
    for (int m = 0; m < 14; ++m) { float d = t[m+1] - t[m]; p[15+m] = 1.f / ((d == 0.f) ? 1.f : d); }
#pragma unroll
    for (int m = 0; m < 13; ++m) { float d = t[m+2] - t[m]; p[29+m] = 1.f / ((d == 0.f) ? 1.f : d); }
#pragma unroll
    for (int m = 0; m < 12; ++m) { float d = t[m+3] - t[m]; p[42+m] = 1.f / ((d == 0.f) ? 1.f : d); }
#pragma unroll
    for (int m = 54; m < 64; ++m) p[m] = 0.f;
}

// ---------------- kernel 2: pack [coeffs | base_weight] to fp16 ------------
__global__ void kan_packw(const float* __restrict__ coeffs, const float* __restrict__ bw,
                          _Float16* __restrict__ Wh) {
    int idx = blockIdx.x * 256 + threadIdx.x;   // idx = o*512 + i
    const float* src = coeffs + (size_t)idx * 11;
    union { _Float16 h[12]; float2 f2[3]; } u;
#pragma unroll
    for (int c = 0; c < 11; ++c) u.h[c] = (_Float16)src[c];
    u.h[11] = (_Float16)bw[idx];
    float2* dst = (float2*)(Wh + (size_t)idx * FPI);
    dst[0] = u.f2[0]; dst[1] = u.f2[1]; dst[2] = u.f2[2];
}

// ---------------- kernel 3: featurize, wave = dim (params in SGPRs) --------
// block: 1024 threads = 16 waves; 64 rows/block; 32 super-steps x 16 dims.
__launch_bounds__(1024, 4)
__global__ void kan_feat(const float* __restrict__ x, const float* __restrict__ P,
                         _Float16* __restrict__ F, int row0) {
    __shared__ float xl[64][17];                      // padded: conflict-free col reads
    __shared__ __align__(16) _Float16 Fl[64][208];    // 16B-aligned rows
    const int tid = threadIdx.x;
    const int l = tid & 63;
    const int w = __builtin_amdgcn_readfirstlane(tid >> 6);   // wave id 0..15
    const int r0 = row0 + blockIdx.x * 64;

    for (int ss = 0; ss < 32; ++ss) {
        const int d0 = ss * 16;
        {   // stage x chunk [64 rows][16 dims], coalesced 64B/row
            const int row = tid >> 4, col = tid & 15;
            xl[row][col] = x[(size_t)(r0 + row) * IN_DIM + d0 + col];
        }
        __syncthreads();
        {   // dense Cox-de Boor, dim = d0+w (wave-uniform -> s_load params)
            const float* ps = P + (size_t)(d0 + w) * PSTRIDE;
            const float X = xl[l][w];
            float b[14];
#pragma unroll
            for (int m = 0; m < 14; ++m)
                b[m] = (X >= ps[m] && X < ps[m + 1]) ? 1.f : 0.f;
#pragma unroll
            for (int m = 0; m < 13; ++m)
                b[m] = ((X - ps[m]) * ps[15 + m]) * b[m] + ((ps[m + 2] - X) * ps[16 + m]) * b[m + 1];
#pragma unroll
            for (int m = 0; m < 12; ++m)
                b[m] = ((X - ps[m]) * ps[29 + m]) * b[m] + ((ps[m + 3] - X) * ps[30 + m]) * b[m + 1];
#pragma unroll
            for (int m = 0; m < 11; ++m)
                b[m] = ((X - ps[m]) * ps[42 + m]) * b[m] + ((ps[m + 4] - X) * ps[43 + m]) * b[m + 1];
            const float sil = X / (1.f + __expf(-X));
            half4 h0 = { (_Float16)b[0], (_Float16)b[1], (_Float16)b[2],  (_Float16)b[3] };
            half4 h1 = { (_Float16)b[4], (_Float16)b[5], (_Float16)b[6],  (_Float16)b[7] };
            half4 h2 = { (_Float16)b[8], (_Float16)b[9], (_Float16)b[10], (_Float16)sil  };
            *(half4*)&Fl[l][w * 12]     = h0;
            *(half4*)&Fl[l][w * 12 + 4] = h1;
            *(half4*)&Fl[l][w * 12 + 8] = h2;
        }
        __syncthreads();
        // write-out: 64 rows x 384B contiguous -> 1536 x 16B chunks
#pragma unroll
        for (int rr = 0; rr < 2; ++rr) {
            int ci = tid + rr * 1024;
            if (ci < 1536) {
                int row = ci / 24, c16 = ci - row * 24;
                float4 v = *(const float4*)&Fl[row][c16 * 8];
                *(float4*)((char*)F + (size_t)(r0 + row) * (KTOT * 2) + (size_t)d0 * 24 + c16 * 16) = v;
            }
        }
    }
}

// ---------------- kernel 4: GEMM, BK=64, XOR-swizzled LDS ------------------
// Swizzle (involution, both sides): byte ^= ((row&7)<<4) within a [128][128B]
// tile. gload_lds dest stays LINEAR; the global SOURCE is pre-swizzled; the
// ds_read applies the same XOR -> 16-lane column reads are 2-way = free.
#define BKH 64                // K-step in halfs (128B per row)
#define NS2 (KTOT / BKH)      // 96 steps
__launch_bounds__(256, 2)
__global__ void kan_gemm(const _Float16* __restrict__ F, const _Float16* __restrict__ Wh,
                         const float* __restrict__ x, const float* __restrict__ rsp,
                         float* __restrict__ out, int row0) {
    __shared__ __align__(16) _Float16 As[128 * BKH];   // 16 KB
    __shared__ __align__(16) _Float16 Bs[128 * BKH];   // 16 KB
    int bid = blockIdx.x;
    const int nwg = gridDim.x;
    if ((nwg & 7) == 0) bid = (bid & 7) * (nwg >> 3) + (bid >> 3);  // XCD swizzle
    const int rt = bid >> 2, ct = bid & 3;
    const int lr0 = rt * 128, o0 = ct * 128;
    const int tid = threadIdx.x, l = tid & 63, w = tid >> 6;
    const int wr = (w >> 1) * 64, wc = (w & 1) * 64;

    f32x4 acc[4][4];
    const f32x4 zz = {0.f, 0.f, 0.f, 0.f};
#pragma unroll
    for (int m = 0; m < 4; ++m)
#pragma unroll
        for (int n = 0; n < 4; ++n) acc[m][n] = zz;

    // staging: 1024 granules of 16B per tile; thread owns lam = r*256+tid.
    // LDS dest linear (lam*16); global source col pre-swizzled.
    const char* pA[4];
    const char* pB[4];
#pragma unroll
    for (int r = 0; r < 4; ++r) {
        const int lam = r * 256 + tid;
        const int row = lam >> 3;                         // 0..127
        const int scol = ((lam ^ (lam >> 3)) & 7) * 16;   // swizzled col-byte
        pA[r] = (const char*)F  + (size_t)(row0 + lr0 + row) * (KTOT * 2) + scol;
        pB[r] = (const char*)Wh + (size_t)(o0 + row) * (KTOT * 2) + scol;
    }

    const int xv = (l & 7) << 4;                          // read-side XOR
    const int arow = wr + (l & 15), brow = wc + (l & 15);

    for (int s = 0; s < NS2; ++s) {
        const int kb = s * 128;                           // bytes into the K dim
#pragma unroll
        for (int r = 0; r < 4; ++r) {
            gload16(pA[r] + kb, (char*)As + (r * 256 + tid) * 16);
            gload16(pB[r] + kb, (char*)Bs + (r * 256 + tid) * 16);
        }
        __syncthreads();                                  // vmcnt(0) drain: tiles ready
#pragma unroll
        for (int kk = 0; kk < 2; ++kk) {
            const int colb = ((kk * 64) | ((l >> 4) * 16)) ^ xv;
            half8 af[4], bf[4];
#pragma unroll
            for (int m = 0; m < 4; ++m)
                af[m] = *(const half8*)((const char*)As + (arow + m * 16) * 128 + colb);
#pragma unroll
            for (int n = 0; n < 4; ++n)
                bf[n] = *(const half8*)((const char*)Bs + (brow + n * 16) * 128 + colb);
#pragma unroll
            for (int m = 0; m < 4; ++m)
#pragma unroll
                for (int n = 0; n < 4; ++n)
                    acc[m][n] = __builtin_amdgcn_mfma_f32_16x16x32_f16(af[m], bf[n], acc[m][n], 0, 0, 0);
        }
        __syncthreads();                                  // reads done before re-stage
    }

    // epilogue: + rs*x, tanh, store. D map: col = l&15, row = (l>>4)*4 + reg
    const float rs = rsp[0];
#pragma unroll
    for (int m = 0; m < 4; ++m)
#pragma unroll
        for (int n = 0; n < 4; ++n)
#pragma unroll
            for (int j = 0; j < 4; ++j) {
                const int r = row0 + lr0 + wr + m * 16 + (l >> 4) * 4 + j;
                const int c = o0 + wc + n * 16 + (l & 15);
                float v = acc[m][n][j] + rs * x[(size_t)r * IN_DIM + c];
                float e = __expf(2.f * v);                // tanh = 1 - 2/(e^2v+1)
                out[(size_t)r * OUT_DIM + c] = 1.f - 2.f / (e + 1.f);
            }
}

extern "C" void kernel_launch(void* const* d_in, const int* in_sizes, int n_in,
                              void* d_out, int out_size, void* d_ws, size_t ws_size,
                              hipStream_t stream) {
    const float* x      = (const float*)d_in[0];
    const float* coeffs = (const float*)d_in[1];
    const float* bw     = (const float*)d_in[2];
    const float* gsl    = (const float*)d_in[3];
    const float* gstart = (const float*)d_in[4];
    const float* rs     = (const float*)d_in[5];
    float* out = (float*)d_out;
    float* P   = (float*)d_ws;
    _Float16* Wh = (_Float16*)(P + WS_WH_OFF_F);
    _Float16* F  = (_Float16*)((char*)d_ws + WS_F_OFF_B);

    kan_prep<<<2, 256, 0, stream>>>(gsl, gstart, P);
    kan_packw<<<1024, 256, 0, stream>>>(coeffs, bw, Wh);

    int CH = NBATCH;
    while (CH > 128 && WS_F_OFF_B + (size_t)CH * KTOT * 2 > ws_size) CH >>= 1;
    if (WS_F_OFF_B + (size_t)CH * KTOT * 2 > ws_size) return;  // ws too small: fail loud

    for (int row0 = 0; row0 < NBATCH; row0 += CH) {
        kan_feat<<<CH / 64, 1024, 0, stream>>>(x, P, F, row0);
        kan_gemm<<<(CH / 128) * 4, 256, 0, stream>>>(F, Wh, x, rs, out, row0);
    }
}